// Round 1
// baseline (9870.109 us; speedup 1.0000x reference)
//
#include <hip/hip_runtime.h>
#include <hip/hip_cooperative_groups.h>
#include <math.h>

namespace cg = cooperative_groups;

#define Bc 32
#define Tc 128
#define TYc 64
#define Ec 512
#define Hc 512
#define Vc 32000
#define HHc 256

typedef unsigned short u16;
typedef unsigned int u32;
typedef short bf16x8 __attribute__((ext_vector_type(8)));
typedef float f32x4 __attribute__((ext_vector_type(4)));

static __device__ __forceinline__ float sigm(float x) { return 1.0f / (1.0f + expf(-x)); }

static __device__ __forceinline__ u16 f2bf(float f) {
    u32 u = __float_as_uint(f);
    u += 0x7FFFu + ((u >> 16) & 1u);  // RNE
    return (u16)(u >> 16);
}

// ---------------- zero init ----------------
__global__ void k_zero(float* __restrict__ p, int n) {
    int i = blockIdx.x * 256 + threadIdx.x;
    if (i < n) p[i] = 0.0f;
}

// ---------------- pad-aware reverse scatter ----------------
__global__ void k_rev(const int* __restrict__ x, const float* __restrict__ xm, int* __restrict__ xb) {
    int b = blockIdx.x, tid = threadIdx.x;  // 128 threads
    __shared__ float r[128];
    r[tid] = xm[b * Tc + tid];
    __syncthreads();
    for (int o = 64; o > 0; o >>= 1) { if (tid < o) r[tid] += r[tid + o]; __syncthreads(); }
    int pad = Tc - (int)(r[0] + 0.5f);
    xb[b * Tc + tid] = 0;
    __syncthreads();
    int rev = Tc - 1 - tid - pad;
    if (rev < 0) rev = 0;
    xb[b * Tc + rev] = x[b * Tc + tid];
}

// ---------------- embedding gather, writes bf16 (x, x_back, y) ----------------
__global__ void k_embed(const int* __restrict__ x, const int* __restrict__ xb, const int* __restrict__ y,
                        const float* __restrict__ emb, u16* __restrict__ xe, u16* __restrict__ xbe,
                        u16* __restrict__ ye) {
    int r = blockIdx.x;
    int tid = threadIdx.x;  // 128 threads, 4 elems each
    int tok;
    u16* dst;
    if (r < Bc * Tc) { tok = x[r]; dst = xe + (size_t)r * Ec; }
    else if (r < 2 * Bc * Tc) { int rr = r - Bc * Tc; tok = xb[rr]; dst = xbe + (size_t)rr * Ec; }
    else { int rr = r - 2 * Bc * Tc; tok = y[rr]; dst = ye + (size_t)rr * Ec; }
    float4 v = ((const float4*)(emb + (size_t)tok * Ec))[tid];
    ushort4 o;
    o.x = f2bf(v.x); o.y = f2bf(v.y); o.z = f2bf(v.z); o.w = f2bf(v.w);
    ((ushort4*)dst)[tid] = o;
}

// ---------------- fp32 -> bf16 cast (generic, n mult of 4) ----------------
__global__ void k_castv(const float* __restrict__ s, u16* __restrict__ d, int n) {
    int i = (blockIdx.x * 256 + threadIdx.x) * 4;
    if (i < n) {
        float4 v = *(const float4*)(s + i);
        d[i + 0] = f2bf(v.x); d[i + 1] = f2bf(v.y); d[i + 2] = f2bf(v.z); d[i + 3] = f2bf(v.w);
    }
}

// ---------------- bias sum ----------------
__global__ void k_bsum(const float* __restrict__ a, const float* __restrict__ b, float* __restrict__ d, int n) {
    int i = blockIdx.x * 256 + threadIdx.x;
    if (i < n) d[i] = a[i] + b[i];
}

// ---------------- fp32 NT GEMM (fallback only) ----------------
__global__ __launch_bounds__(256) void k_gemm_nt(const float* __restrict__ A, const float* __restrict__ W,
                                                 const float* __restrict__ bias1, const float* __restrict__ bias2,
                                                 float* __restrict__ C, int M, int N, int K) {
    __shared__ float As[16][64];
    __shared__ float Bs[16][64];
    int tid = threadIdx.x;
    int m0 = blockIdx.y << 6;
    int n0 = blockIdx.x << 6;
    int lr = tid >> 2;
    int lc = (tid & 3) << 2;
    const float* Ap = A + (size_t)(m0 + lr) * K + lc;
    const float* Wp = W + (size_t)(n0 + lr) * K + lc;
    int tx = tid & 15, ty = tid >> 4;
    float acc[4][4] = {{0.f}};
    for (int k0 = 0; k0 < K; k0 += 16) {
        float4 av = *(const float4*)(Ap + k0);
        float4 wv = *(const float4*)(Wp + k0);
        __syncthreads();
        As[lc + 0][lr] = av.x; As[lc + 1][lr] = av.y; As[lc + 2][lr] = av.z; As[lc + 3][lr] = av.w;
        Bs[lc + 0][lr] = wv.x; Bs[lc + 1][lr] = wv.y; Bs[lc + 2][lr] = wv.z; Bs[lc + 3][lr] = wv.w;
        __syncthreads();
#pragma unroll
        for (int k = 0; k < 16; ++k) {
            float a0 = As[k][(ty << 2) + 0], a1 = As[k][(ty << 2) + 1];
            float a2 = As[k][(ty << 2) + 2], a3 = As[k][(ty << 2) + 3];
            float b0 = Bs[k][(tx << 2) + 0], b1 = Bs[k][(tx << 2) + 1];
            float b2 = Bs[k][(tx << 2) + 2], b3 = Bs[k][(tx << 2) + 3];
            acc[0][0] += a0 * b0; acc[0][1] += a0 * b1; acc[0][2] += a0 * b2; acc[0][3] += a0 * b3;
            acc[1][0] += a1 * b0; acc[1][1] += a1 * b1; acc[1][2] += a1 * b2; acc[1][3] += a1 * b3;
            acc[2][0] += a2 * b0; acc[2][1] += a2 * b1; acc[2][2] += a2 * b2; acc[2][3] += a2 * b3;
            acc[3][0] += a3 * b0; acc[3][1] += a3 * b1; acc[3][2] += a3 * b2; acc[3][3] += a3 * b3;
        }
    }
#pragma unroll
    for (int i = 0; i < 4; ++i) {
        int m = m0 + (ty << 2) + i;
#pragma unroll
        for (int j = 0; j < 4; ++j) {
            int n = n0 + (tx << 2) + j;
            float bs = (bias1 ? bias1[n] : 0.f) + (bias2 ? bias2[n] : 0.f);
            C[(size_t)m * N + n] = acc[i][j] + bs;
        }
    }
}

// ---------------- fp32 -> bf16 cast (W_out then outH, one grid) ----------------
__global__ void k_cast(const float* __restrict__ W, const float* __restrict__ Hh,
                       u16* __restrict__ Wb, u16* __restrict__ Ab, int nW, int nA) {
    int i = (blockIdx.x * 256 + threadIdx.x) * 4;
    if (i < nW) {
        float4 v = *(const float4*)(W + i);
        Wb[i + 0] = f2bf(v.x); Wb[i + 1] = f2bf(v.y); Wb[i + 2] = f2bf(v.z); Wb[i + 3] = f2bf(v.w);
    } else {
        int j = i - nW;
        if (j < nA) {
            float4 v = *(const float4*)(Hh + j);
            Ab[j + 0] = f2bf(v.x); Ab[j + 1] = f2bf(v.y); Ab[j + 2] = f2bf(v.z); Ab[j + 3] = f2bf(v.w);
        }
    }
}

// ---------------- bf16 MFMA NT GEMM: C[m,n] = A[m,:].W[n,:] + bias ----------------
#define LDAp 40  // padded LDS row stride (bf16 elems)
__global__ __launch_bounds__(256) void k_gemm_bf16(const u16* __restrict__ A, const u16* __restrict__ W,
                                                   const float* __restrict__ bias, float* __restrict__ C,
                                                   int M, int N, int K) {
    __shared__ u16 As[128 * LDAp];
    __shared__ u16 Bs[128 * LDAp];
    int tid = threadIdx.x;
    int m0 = blockIdx.y << 7;
    int n0 = blockIdx.x << 7;

    int r4 = tid >> 2;
    int c8 = (tid & 3) << 3;
    const u16* Ag = A + (size_t)(m0 + r4) * K + c8;
    const u16* Wg = W + (size_t)(n0 + r4) * K + c8;
    u16* AsW = &As[r4 * LDAp + c8];
    u16* BsW = &Bs[r4 * LDAp + c8];

    int wv = tid >> 6;
    int lane = tid & 63;
    int wm = (wv >> 1) << 6;
    int wn = (wv & 1) << 6;
    int lr = lane & 15;
    int kq = (lane >> 4) << 3;
    const u16* Ard = &As[(wm + lr) * LDAp + kq];
    const u16* Brd = &Bs[(wn + lr) * LDAp + kq];

    f32x4 acc[4][4];
#pragma unroll
    for (int i = 0; i < 4; ++i)
#pragma unroll
        for (int j = 0; j < 4; ++j) acc[i][j] = (f32x4){0.f, 0.f, 0.f, 0.f};

    for (int k0 = 0; k0 < K; k0 += 32) {
        uint4 a0 = *(const uint4*)(Ag + k0);
        uint4 a1 = *(const uint4*)(Ag + (size_t)64 * K + k0);
        uint4 b0 = *(const uint4*)(Wg + k0);
        uint4 b1 = *(const uint4*)(Wg + (size_t)64 * K + k0);
        __syncthreads();
        *(uint4*)AsW = a0;
        *(uint4*)(AsW + 64 * LDAp) = a1;
        *(uint4*)BsW = b0;
        *(uint4*)(BsW + 64 * LDAp) = b1;
        __syncthreads();
        bf16x8 af[4], bfr[4];
#pragma unroll
        for (int i = 0; i < 4; ++i) {
            af[i] = *(const bf16x8*)(Ard + i * 16 * LDAp);
            bfr[i] = *(const bf16x8*)(Brd + i * 16 * LDAp);
        }
#pragma unroll
        for (int i = 0; i < 4; ++i)
#pragma unroll
            for (int j = 0; j < 4; ++j)
                acc[i][j] = __builtin_amdgcn_mfma_f32_16x16x32_bf16(af[i], bfr[j], acc[i][j], 0, 0, 0);
    }

    int rq = (lane >> 4) << 2;
#pragma unroll
    for (int i = 0; i < 4; ++i) {
#pragma unroll
        for (int j = 0; j < 4; ++j) {
            int n = n0 + wn + j * 16 + lr;
            float bs = bias[n];
            size_t base = (size_t)(m0 + wm + i * 16 + rq) * N + n;
#pragma unroll
            for (int r = 0; r < 4; ++r)
                C[base + (size_t)r * N] = acc[i][j][r] + bs;
        }
    }
}

// ---------------- encoder step (fallback path) ----------------
__global__ __launch_bounds__(256) void k_enc_step(
    const float* __restrict__ gxf, const float* __restrict__ gxb,
    const float* __restrict__ whf, const float* __restrict__ whb,
    const float* __restrict__ hfp, const float* __restrict__ cfp, float* __restrict__ hfn, float* __restrict__ cfn,
    const float* __restrict__ hbp, const float* __restrict__ cbp, float* __restrict__ hbn, float* __restrict__ cbn,
    float* __restrict__ hid, float* __restrict__ cel, int t) {
    int dir = blockIdx.z;
    const float* gx = dir ? gxb : gxf;
    const float* wh = dir ? whb : whf;
    const float* hp = dir ? hbp : hfp;
    const float* cp = dir ? cbp : cfp;
    float* hn = dir ? hbn : hfn;
    float* cn = dir ? cbn : cfn;
    int hoff = dir ? HHc : 0;
    int b = blockIdx.y;
    int chunk = blockIdx.x;
    int tid = threadIdx.x;
    __shared__ float hs[HHc];
    __shared__ float gv[4][64];
    hs[tid] = hp[b * HHc + tid];
    __syncthreads();
    int gate = tid >> 6;
    int jj = (chunk << 6) + (tid & 63);
    int n = gate * HHc + jj;
    const float* w = wh + (size_t)n * HHc;
    float s = gx[(size_t)(b * Tc + t) * (4 * HHc) + n];
#pragma unroll 8
    for (int k = 0; k < HHc; k += 4) {
        float4 wv = *(const float4*)(w + k);
        s += wv.x * hs[k] + wv.y * hs[k + 1] + wv.z * hs[k + 2] + wv.w * hs[k + 3];
    }
    gv[gate][tid & 63] = s;
    __syncthreads();
    if (tid < 64) {
        int j = (chunk << 6) + tid;
        float c = sigm(gv[1][tid]) * cp[b * HHc + j] + sigm(gv[0][tid]) * tanhf(gv[2][tid]);
        float h = sigm(gv[3][tid]) * tanhf(c);
        hn[b * HHc + j] = h;
        cn[b * HHc + j] = c;
        size_t o = (size_t)(b * Tc + t) * Hc + hoff + j;
        hid[o] = h;
        cel[o] = c;
    }
}

// ---------------- fused encoder recurrence (cooperative, W_hh in registers) ----------------
// grid dim3(4, Bc, 2) = 256 blocks x 256 threads. State hA/cA <-> hB/cB ping-pong, layout [dir][b][HH].
__global__ __launch_bounds__(256, 1) void k_enc_all(
    const float* __restrict__ gxf, const float* __restrict__ gxb,
    const float* __restrict__ whf, const float* __restrict__ whb,
    float* __restrict__ hA, float* __restrict__ cA,
    float* __restrict__ hB, float* __restrict__ cB,
    float* __restrict__ hid, float* __restrict__ cel) {
    cg::grid_group gg = cg::this_grid();
    int chunk = blockIdx.x, b = blockIdx.y, dir = blockIdx.z, tid = threadIdx.x;
    const float* gx = dir ? gxb : gxf;
    const float* wh = dir ? whb : whf;
    int gate = tid >> 6;
    int jj = (chunk << 6) + (tid & 63);
    int n = gate * HHc + jj;
    int sidx = (dir * Bc + b) * HHc;
    // W_hh row for this thread's output, register-resident (256 VGPRs)
    float4 w[64];
    const float* wr = wh + (size_t)n * HHc;
#pragma unroll
    for (int i = 0; i < 64; ++i) w[i] = *(const float4*)(wr + 4 * i);
    __shared__ float hs[HHc];
    __shared__ float gv[4][64];
    for (int t = 0; t < Tc; ++t) {
        const float* hp = (t & 1) ? hB : hA;
        const float* cp = (t & 1) ? cB : cA;
        float* hn = (t & 1) ? hA : hB;
        float* cn = (t & 1) ? cA : cB;
        hs[tid] = hp[sidx + tid];
        __syncthreads();
        float s = gx[(size_t)(b * Tc + t) * (4 * HHc) + n];
#pragma unroll
        for (int i = 0; i < 64; ++i)
            s += w[i].x * hs[4 * i] + w[i].y * hs[4 * i + 1] + w[i].z * hs[4 * i + 2] + w[i].w * hs[4 * i + 3];
        gv[gate][tid & 63] = s;
        __syncthreads();
        if (tid < 64) {
            int j = (chunk << 6) + tid;
            float c = sigm(gv[1][tid]) * cp[sidx + j] + sigm(gv[0][tid]) * tanhf(gv[2][tid]);
            float h = sigm(gv[3][tid]) * tanhf(c);
            hn[sidx + j] = h;
            cn[sidx + j] = c;
            size_t o = (size_t)(b * Tc + t) * Hc + dir * HHc + j;
            hid[o] = h;
            cel[o] = c;
        }
        gg.sync();
    }
}

// ---------------- mean over T ----------------
__global__ void k_mean(const float* __restrict__ hid, const float* __restrict__ cel,
                       float* __restrict__ dh, float* __restrict__ dc) {
    int b = blockIdx.x, tid = threadIdx.x;  // 256
    for (int j = tid; j < Hc; j += 256) {
        float sh = 0.f, sc_ = 0.f;
        for (int t = 0; t < Tc; ++t) {
            size_t o = (size_t)(b * Tc + t) * Hc + j;
            sh += hid[o];
            sc_ += cel[o];
        }
        dh[b * Hc + j] = sh * (1.0f / Tc);
        dc[b * Hc + j] = sc_ * (1.0f / Tc);
    }
}

// ---------------- decoder LSTM step (fallback path) ----------------
__global__ __launch_bounds__(256) void k_dec_step(const float* __restrict__ gy, const float* __restrict__ whd,
                                                  const float* __restrict__ hprev, int hstride,
                                                  const float* __restrict__ cp, float* __restrict__ cn,
                                                  float* __restrict__ outH, int t) {
    int b = blockIdx.y;
    int chunk = blockIdx.x;
    int tid = threadIdx.x;
    __shared__ float hs[Hc];
    __shared__ float gv[4][64];
    hs[tid] = hprev[(size_t)b * hstride + tid];
    hs[tid + 256] = hprev[(size_t)b * hstride + tid + 256];
    __syncthreads();
    int gate = tid >> 6;
    int jj = (chunk << 6) + (tid & 63);
    int n = gate * Hc + jj;
    const float* w = whd + (size_t)n * Hc;
    float s = gy[(size_t)(b * TYc + t) * (4 * Hc) + n];
#pragma unroll 8
    for (int k = 0; k < Hc; k += 4) {
        float4 wv = *(const float4*)(w + k);
        s += wv.x * hs[k] + wv.y * hs[k + 1] + wv.z * hs[k + 2] + wv.w * hs[k + 3];
    }
    gv[gate][tid & 63] = s;
    __syncthreads();
    if (tid < 64) {
        int j = (chunk << 6) + tid;
        float c = sigm(gv[1][tid]) * cp[b * Hc + j] + sigm(gv[0][tid]) * tanhf(gv[2][tid]);
        float h = sigm(gv[3][tid]) * tanhf(c);
        cn[b * Hc + j] = c;
        outH[(size_t)(b * TYc + t) * (2 * Hc) + j] = h;
    }
}

// ---------------- fused decoder recurrence (cooperative; attention hoisted out) ----------------
// grid 256 blocks x 256 threads. Phase G: gate preacts, n-chunked across blocks (W reuse over all b).
// Phase U: h/c update distributed over all blocks. 2 grid syncs per step.
__global__ __launch_bounds__(256, 1) void k_dec_all(
    const float* __restrict__ gy, const float* __restrict__ whd,
    const float* __restrict__ dh0, const float* __restrict__ dc0,
    float* __restrict__ c0, float* __restrict__ c1,
    float* __restrict__ gtmp, float* __restrict__ outH) {
    cg::grid_group gg = cg::this_grid();
    int bid = blockIdx.x, tid = threadIdx.x;
    int r = tid & 7, b = tid >> 3;   // 32 b x 8 n per block
    int n = bid * 8 + r;
    const float* w = whd + (size_t)n * Hc;
    for (int t = 0; t < TYc; ++t) {
        // ---- phase G: gate preact for (b, n) ----
        const float* hprev = (t == 0) ? (dh0 + (size_t)b * Hc)
                                      : (outH + (size_t)(b * TYc + t - 1) * (2 * Hc));
        float s = gy[(size_t)(b * TYc + t) * (4 * Hc) + n];
#pragma unroll 8
        for (int k = 0; k < Hc; k += 4) {
            float4 wv = *(const float4*)(w + k);
            float4 hv = *(const float4*)(hprev + k);
            s += wv.x * hv.x + wv.y * hv.y + wv.z * hv.z + wv.w * hv.w;
        }
        gtmp[b * (4 * Hc) + n] = s;
        gg.sync();
        // ---- phase U: h/c update, 16384 items over first 64 lanes of each block ----
        if (tid < 64) {
            int idx = bid * 64 + tid;
            int ub = idx >> 9;
            int uj = idx & 511;
            const float* cp = (t == 0) ? dc0 : ((t & 1) ? c1 : c0);
            float* cn = (t & 1) ? c0 : c1;
            float gi = gtmp[ub * 2048 + uj];
            float gf_ = gtmp[ub * 2048 + 512 + uj];
            float ggt = gtmp[ub * 2048 + 1024 + uj];
            float go = gtmp[ub * 2048 + 1536 + uj];
            float c = sigm(gf_) * cp[ub * Hc + uj] + sigm(gi) * tanhf(ggt);
            float h = sigm(go) * tanhf(c);
            cn[ub * Hc + uj] = c;
            outH[(size_t)(ub * TYc + t) * (2 * Hc) + uj] = h;
        }
        gg.sync();
    }
}

// ---------------- batched attention (all (b,t) at once; identical math to old k_attn) ----------------
__global__ __launch_bounds__(128) void k_attn_all(const float* __restrict__ hid, float* __restrict__ outH, int t0) {
    int b = blockIdx.x, t = t0 + blockIdx.y, tid = threadIdx.x;  // 128
    __shared__ float hq[Hc];
    __shared__ float sc[Tc];
    __shared__ float red[128];
    const float* hrow = outH + (size_t)(b * TYc + t) * (2 * Hc);
    for (int k = tid; k < Hc; k += 128) hq[k] = hrow[k];
    __syncthreads();
    const float* hr = hid + (size_t)(b * Tc + tid) * Hc;
    float s = 0.f;
#pragma unroll 8
    for (int k = 0; k < Hc; k += 4) {
        float4 hv = *(const float4*)(hr + k);
        s += hv.x * hq[k] + hv.y * hq[k + 1] + hv.z * hq[k + 2] + hv.w * hq[k + 3];
    }
    red[tid] = s;
    __syncthreads();
    for (int o = 64; o > 0; o >>= 1) { if (tid < o) red[tid] = fmaxf(red[tid], red[tid + o]); __syncthreads(); }
    float mx = red[0];
    __syncthreads();
    float e = expf(s - mx);
    sc[tid] = e;
    red[tid] = e;
    __syncthreads();
    for (int o = 64; o > 0; o >>= 1) { if (tid < o) red[tid] += red[tid + o]; __syncthreads(); }
    float inv = 1.0f / red[0];
    for (int j = tid; j < Hc; j += 128) {
        float acc = 0.f;
        for (int tt = 0; tt < Tc; ++tt) acc += sc[tt] * hid[(size_t)(b * Tc + tt) * Hc + j];
        outH[(size_t)(b * TYc + t) * (2 * Hc) + Hc + j] = acc * inv;
    }
}

// ---------------- in-place log-softmax over V ----------------
__global__ __launch_bounds__(256) void k_logsm(float* __restrict__ P) {
    int row = blockIdx.x, tid = threadIdx.x;
    float* p = P + (size_t)row * Vc;
    float m = -1e30f, s = 0.f;
    for (int i = tid; i < Vc; i += 256) {
        float v = p[i];
        float nm = fmaxf(m, v);
        s = s * expf(m - nm) + expf(v - nm);
        m = nm;
    }
    __shared__ float ms[256], ss[256];
    ms[tid] = m; ss[tid] = s;
    __syncthreads();
    for (int o = 128; o > 0; o >>= 1) {
        if (tid < o) {
            float m2 = ms[tid + o], s2 = ss[tid + o];
            float nm = fmaxf(ms[tid], m2);
            ss[tid] = ss[tid] * expf(ms[tid] - nm) + s2 * expf(m2 - nm);
            ms[tid] = nm;
        }
        __syncthreads();
    }
    float lse = ms[0] + logf(ss[0]);
    for (int i = tid; i < Vc; i += 256) p[i] -= lse;
}

extern "C" void kernel_launch(void* const* d_in, const int* in_sizes, int n_in,
                              void* d_out, int out_size, void* d_ws, size_t ws_size,
                              hipStream_t stream) {
    const int* x = (const int*)d_in[0];
    const float* xm = (const float*)d_in[1];
    const int* y = (const int*)d_in[2];
    const float* emb = (const float*)d_in[3];
    const float* w_ih_f = (const float*)d_in[4];
    const float* w_hh_f = (const float*)d_in[5];
    const float* b_ih_f = (const float*)d_in[6];
    const float* b_hh_f = (const float*)d_in[7];
    const float* w_ih_b = (const float*)d_in[8];
    const float* w_hh_b = (const float*)d_in[9];
    const float* b_ih_b = (const float*)d_in[10];
    const float* b_hh_b = (const float*)d_in[11];
    const float* w_ih_d = (const float*)d_in[12];
    const float* w_hh_d = (const float*)d_in[13];
    const float* b_ih_d = (const float*)d_in[14];
    const float* b_hh_d = (const float*)d_in[15];
    const float* W_out = (const float*)d_in[16];
    const float* b_out = (const float*)d_in[17];

    float* out = (float*)d_out;
    float* logp = out;                           // (B*TY, V)
    float* outH = out + (size_t)Bc * TYc * Vc;   // (B*TY, 2H) — final output region

    // Scratch arena inside logp region (dead by the time the logits GEMM writes it).
    const size_t BTE = (size_t)Bc * Tc * Ec;     // 2,097,152
    const size_t BTYE = (size_t)Bc * TYc * Ec;   // 1,048,576
    u16* xeb = (u16*)out;
    u16* xbeb = xeb + BTE;
    u16* yeb = xbeb + BTE;
    float* gf = out + (2 * BTE + BTYE) / 2;
    float* gb = gf + (size_t)Bc * Tc * 4 * HHc;
    float* gd = gb + (size_t)Bc * Tc * 4 * HHc;
    float* hid = gd + (size_t)Bc * TYc * 4 * Hc;
    float* cel = hid + (size_t)Bc * Tc * Hc;
    float* hA = cel + (size_t)Bc * Tc * Hc;
    float* cA = hA + 2 * Bc * HHc;
    float* hB = cA + 2 * Bc * HHc;
    float* cB = hB + 2 * Bc * HHc;
    float* dh0 = cB + 2 * Bc * HHc;
    float* dc0 = dh0 + Bc * Hc;
    float* c0 = dc0 + Bc * Hc;
    float* c1 = c0 + Bc * Hc;
    float* gtmp = c1 + Bc * Hc;
    float* bsf = gtmp + Bc * 4 * Hc;
    float* bsb = bsf + 4 * HHc;
    float* bsd = bsb + 4 * HHc;
    u16* wfb = (u16*)(bsd + 4 * Hc);
    u16* wbb = wfb + (size_t)4 * HHc * Ec;
    u16* wdb = wbb + (size_t)4 * HHc * Ec;
    int* xb = (int*)(wdb + (size_t)4 * Hc * Ec);

    (void)in_sizes; (void)n_in; (void)out_size;

    k_rev<<<Bc, 128, 0, stream>>>(x, xm, xb);
    k_zero<<<(8 * Bc * HHc + 255) / 256, 256, 0, stream>>>(hA, 8 * Bc * HHc);
    k_embed<<<2 * Bc * Tc + Bc * TYc, 128, 0, stream>>>(x, xb, y, emb, xeb, xbeb, yeb);

    // cast input-side weights to bf16, fold biases
    k_castv<<<(4 * HHc * Ec / 4 + 255) / 256, 256, 0, stream>>>(w_ih_f, wfb, 4 * HHc * Ec);
    k_castv<<<(4 * HHc * Ec / 4 + 255) / 256, 256, 0, stream>>>(w_ih_b, wbb, 4 * HHc * Ec);
    k_castv<<<(4 * Hc * Ec / 4 + 255) / 256, 256, 0, stream>>>(w_ih_d, wdb, 4 * Hc * Ec);
    k_bsum<<<(4 * HHc + 255) / 256, 256, 0, stream>>>(b_ih_f, b_hh_f, bsf, 4 * HHc);
    k_bsum<<<(4 * HHc + 255) / 256, 256, 0, stream>>>(b_ih_b, b_hh_b, bsb, 4 * HHc);
    k_bsum<<<(4 * Hc + 255) / 256, 256, 0, stream>>>(b_ih_d, b_hh_d, bsd, 4 * Hc);

    // input-side gate GEMMs via bf16 MFMA
    k_gemm_bf16<<<dim3(4 * HHc / 128, Bc * Tc / 128), 256, 0, stream>>>(xeb, wfb, bsf, gf, Bc * Tc, 4 * HHc, Ec);
    k_gemm_bf16<<<dim3(4 * HHc / 128, Bc * Tc / 128), 256, 0, stream>>>(xbeb, wbb, bsb, gb, Bc * Tc, 4 * HHc, Ec);
    k_gemm_bf16<<<dim3(4 * Hc / 128, Bc * TYc / 128), 256, 0, stream>>>(yeb, wdb, bsd, gd, Bc * TYc, 4 * Hc, Ec);

    // encoder recurrence: one cooperative kernel (fallback: per-step launches)
    {
        const float* a_gxf = gf; const float* a_gxb = gb;
        const float* a_whf = w_hh_f; const float* a_whb = w_hh_b;
        float* a_hA = hA; float* a_cA = cA; float* a_hB = hB; float* a_cB = cB;
        float* a_hid = hid; float* a_cel = cel;
        void* args[] = {&a_gxf, &a_gxb, &a_whf, &a_whb, &a_hA, &a_cA, &a_hB, &a_cB, &a_hid, &a_cel};
        hipError_t e = hipLaunchCooperativeKernel(reinterpret_cast<void*>(k_enc_all),
                                                  dim3(HHc / 64, Bc, 2), dim3(256), args, 0, stream);
        if (e != hipSuccess) {
            for (int t = 0; t < Tc; ++t) {
                const float* hp = (t & 1) ? hB : hA;
                const float* cp = (t & 1) ? cB : cA;
                float* hn = (t & 1) ? hA : hB;
                float* cn = (t & 1) ? cA : cB;
                k_enc_step<<<dim3(HHc / 64, Bc, 2), 256, 0, stream>>>(
                    gf, gb, w_hh_f, w_hh_b,
                    hp, cp, hn, cn,
                    hp + (size_t)Bc * HHc, cp + (size_t)Bc * HHc,
                    hn + (size_t)Bc * HHc, cn + (size_t)Bc * HHc, hid, cel, t);
            }
        }
    }

    k_mean<<<Bc, 256, 0, stream>>>(hid, cel, dh0, dc0);

    // decoder recurrence: one cooperative kernel (attention hoisted out of the loop)
    {
        const float* a_gy = gd; const float* a_whd = w_hh_d;
        const float* a_dh0 = dh0; const float* a_dc0 = dc0;
        float* a_c0 = c0; float* a_c1 = c1; float* a_gt = gtmp; float* a_oH = outH;
        void* args[] = {&a_gy, &a_whd, &a_dh0, &a_dc0, &a_c0, &a_c1, &a_gt, &a_oH};
        hipError_t e = hipLaunchCooperativeKernel(reinterpret_cast<void*>(k_dec_all),
                                                  dim3(256), dim3(256), args, 0, stream);
        if (e != hipSuccess) {
            for (int t = 0; t < TYc; ++t) {
                const float* hprev = (t == 0) ? dh0 : (outH + (size_t)(t - 1) * (2 * Hc));
                int hstride = (t == 0) ? Hc : TYc * 2 * Hc;
                const float* cp = (t == 0) ? dc0 : ((t & 1) ? c1 : c0);
                float* cn = (t & 1) ? c0 : c1;
                k_dec_step<<<dim3(Hc / 64, Bc), 256, 0, stream>>>(gd, w_hh_d, hprev, hstride, cp, cn, outH, t);
            }
        }
    }

    // batched attention over all (b, t) — out of the recurrence critical path
    k_attn_all<<<dim3(Bc, TYc), 128, 0, stream>>>(hid, outH, 0);

    // logits = outH @ W_out^T + b_out
    const int nW = Vc * 2 * Hc;
    const int nA = Bc * TYc * 2 * Hc;
    size_t need = ((size_t)nW + nA) * sizeof(u16);
    if (ws_size >= need) {
        u16* Wb = (u16*)d_ws;
        u16* Ab = Wb + nW;
        k_cast<<<((nW + nA) / 4 + 255) / 256, 256, 0, stream>>>(W_out, outH, Wb, Ab, nW, nA);
        k_gemm_bf16<<<dim3(Vc / 128, Bc * TYc / 128), 256, 0, stream>>>(Ab, Wb, b_out, logp, Bc * TYc, Vc, 2 * Hc);
    } else {
        k_gemm_nt<<<dim3(Vc / 64, Bc * TYc / 64), 256, 0, stream>>>(outH, W_out, b_out, nullptr, logp, Bc * TYc, Vc, 2 * Hc);
    }
    k_logsm<<<Bc * TYc, 256, 0, stream>>>(logp);
}

// Round 2
// 2647.990 us; speedup vs baseline: 3.7274x; 3.7274x over previous
//
#include <hip/hip_runtime.h>
#include <math.h>

#define Bc 32
#define Tc 128
#define TYc 64
#define Ec 512
#define Hc 512
#define Vc 32000
#define HHc 256

typedef unsigned short u16;
typedef unsigned int u32;
typedef short bf16x8 __attribute__((ext_vector_type(8)));
typedef float f32x4 __attribute__((ext_vector_type(4)));

static __device__ __forceinline__ float sigm(float x) { return 1.0f / (1.0f + expf(-x)); }

static __device__ __forceinline__ u16 f2bf(float f) {
    u32 u = __float_as_uint(f);
    u += 0x7FFFu + ((u >> 16) & 1u);  // RNE
    return (u16)(u >> 16);
}

// ---------------- zero init ----------------
__global__ void k_zero(float* __restrict__ p, int n) {
    int i = blockIdx.x * 256 + threadIdx.x;
    if (i < n) p[i] = 0.0f;
}

// ---------------- pad-aware reverse scatter ----------------
__global__ void k_rev(const int* __restrict__ x, const float* __restrict__ xm, int* __restrict__ xb) {
    int b = blockIdx.x, tid = threadIdx.x;  // 128 threads
    __shared__ float r[128];
    r[tid] = xm[b * Tc + tid];
    __syncthreads();
    for (int o = 64; o > 0; o >>= 1) { if (tid < o) r[tid] += r[tid + o]; __syncthreads(); }
    int pad = Tc - (int)(r[0] + 0.5f);
    xb[b * Tc + tid] = 0;
    __syncthreads();
    int rev = Tc - 1 - tid - pad;
    if (rev < 0) rev = 0;
    xb[b * Tc + rev] = x[b * Tc + tid];
}

// ---------------- embedding gather, writes bf16 (x, x_back, y) ----------------
__global__ void k_embed(const int* __restrict__ x, const int* __restrict__ xb, const int* __restrict__ y,
                        const float* __restrict__ emb, u16* __restrict__ xe, u16* __restrict__ xbe,
                        u16* __restrict__ ye) {
    int r = blockIdx.x;
    int tid = threadIdx.x;  // 128 threads, 4 elems each
    int tok;
    u16* dst;
    if (r < Bc * Tc) { tok = x[r]; dst = xe + (size_t)r * Ec; }
    else if (r < 2 * Bc * Tc) { int rr = r - Bc * Tc; tok = xb[rr]; dst = xbe + (size_t)rr * Ec; }
    else { int rr = r - 2 * Bc * Tc; tok = y[rr]; dst = ye + (size_t)rr * Ec; }
    float4 v = ((const float4*)(emb + (size_t)tok * Ec))[tid];
    ushort4 o;
    o.x = f2bf(v.x); o.y = f2bf(v.y); o.z = f2bf(v.z); o.w = f2bf(v.w);
    ((ushort4*)dst)[tid] = o;
}

// ---------------- fp32 -> bf16 cast (generic, n mult of 4) ----------------
__global__ void k_castv(const float* __restrict__ s, u16* __restrict__ d, int n) {
    int i = (blockIdx.x * 256 + threadIdx.x) * 4;
    if (i < n) {
        float4 v = *(const float4*)(s + i);
        d[i + 0] = f2bf(v.x); d[i + 1] = f2bf(v.y); d[i + 2] = f2bf(v.z); d[i + 3] = f2bf(v.w);
    }
}

// ---------------- bias sum ----------------
__global__ void k_bsum(const float* __restrict__ a, const float* __restrict__ b, float* __restrict__ d, int n) {
    int i = blockIdx.x * 256 + threadIdx.x;
    if (i < n) d[i] = a[i] + b[i];
}

// ---------------- fp32 NT GEMM (fallback only) ----------------
__global__ __launch_bounds__(256) void k_gemm_nt(const float* __restrict__ A, const float* __restrict__ W,
                                                 const float* __restrict__ bias1, const float* __restrict__ bias2,
                                                 float* __restrict__ C, int M, int N, int K) {
    __shared__ float As[16][64];
    __shared__ float Bs[16][64];
    int tid = threadIdx.x;
    int m0 = blockIdx.y << 6;
    int n0 = blockIdx.x << 6;
    int lr = tid >> 2;
    int lc = (tid & 3) << 2;
    const float* Ap = A + (size_t)(m0 + lr) * K + lc;
    const float* Wp = W + (size_t)(n0 + lr) * K + lc;
    int tx = tid & 15, ty = tid >> 4;
    float acc[4][4] = {{0.f}};
    for (int k0 = 0; k0 < K; k0 += 16) {
        float4 av = *(const float4*)(Ap + k0);
        float4 wv = *(const float4*)(Wp + k0);
        __syncthreads();
        As[lc + 0][lr] = av.x; As[lc + 1][lr] = av.y; As[lc + 2][lr] = av.z; As[lc + 3][lr] = av.w;
        Bs[lc + 0][lr] = wv.x; Bs[lc + 1][lr] = wv.y; Bs[lc + 2][lr] = wv.z; Bs[lc + 3][lr] = wv.w;
        __syncthreads();
#pragma unroll
        for (int k = 0; k < 16; ++k) {
            float a0 = As[k][(ty << 2) + 0], a1 = As[k][(ty << 2) + 1];
            float a2 = As[k][(ty << 2) + 2], a3 = As[k][(ty << 2) + 3];
            float b0 = Bs[k][(tx << 2) + 0], b1 = Bs[k][(tx << 2) + 1];
            float b2 = Bs[k][(tx << 2) + 2], b3 = Bs[k][(tx << 2) + 3];
            acc[0][0] += a0 * b0; acc[0][1] += a0 * b1; acc[0][2] += a0 * b2; acc[0][3] += a0 * b3;
            acc[1][0] += a1 * b0; acc[1][1] += a1 * b1; acc[1][2] += a1 * b2; acc[1][3] += a1 * b3;
            acc[2][0] += a2 * b0; acc[2][1] += a2 * b1; acc[2][2] += a2 * b2; acc[2][3] += a2 * b3;
            acc[3][0] += a3 * b0; acc[3][1] += a3 * b1; acc[3][2] += a3 * b2; acc[3][3] += a3 * b3;
        }
    }
#pragma unroll
    for (int i = 0; i < 4; ++i) {
        int m = m0 + (ty << 2) + i;
#pragma unroll
        for (int j = 0; j < 4; ++j) {
            int n = n0 + (tx << 2) + j;
            float bs = (bias1 ? bias1[n] : 0.f) + (bias2 ? bias2[n] : 0.f);
            C[(size_t)m * N + n] = acc[i][j] + bs;
        }
    }
}

// ---------------- fp32 -> bf16 cast (W_out then outH, one grid) ----------------
__global__ void k_cast(const float* __restrict__ W, const float* __restrict__ Hh,
                       u16* __restrict__ Wb, u16* __restrict__ Ab, int nW, int nA) {
    int i = (blockIdx.x * 256 + threadIdx.x) * 4;
    if (i < nW) {
        float4 v = *(const float4*)(W + i);
        Wb[i + 0] = f2bf(v.x); Wb[i + 1] = f2bf(v.y); Wb[i + 2] = f2bf(v.z); Wb[i + 3] = f2bf(v.w);
    } else {
        int j = i - nW;
        if (j < nA) {
            float4 v = *(const float4*)(Hh + j);
            Ab[j + 0] = f2bf(v.x); Ab[j + 1] = f2bf(v.y); Ab[j + 2] = f2bf(v.z); Ab[j + 3] = f2bf(v.w);
        }
    }
}

// ---------------- bf16 MFMA NT GEMM: C[m,n] = A[m,:].W[n,:] + bias ----------------
#define LDAp 40  // padded LDS row stride (bf16 elems)
__global__ __launch_bounds__(256) void k_gemm_bf16(const u16* __restrict__ A, const u16* __restrict__ W,
                                                   const float* __restrict__ bias, float* __restrict__ C,
                                                   int M, int N, int K) {
    __shared__ u16 As[128 * LDAp];
    __shared__ u16 Bs[128 * LDAp];
    int tid = threadIdx.x;
    int m0 = blockIdx.y << 7;
    int n0 = blockIdx.x << 7;

    int r4 = tid >> 2;
    int c8 = (tid & 3) << 3;
    const u16* Ag = A + (size_t)(m0 + r4) * K + c8;
    const u16* Wg = W + (size_t)(n0 + r4) * K + c8;
    u16* AsW = &As[r4 * LDAp + c8];
    u16* BsW = &Bs[r4 * LDAp + c8];

    int wv = tid >> 6;
    int lane = tid & 63;
    int wm = (wv >> 1) << 6;
    int wn = (wv & 1) << 6;
    int lr = lane & 15;
    int kq = (lane >> 4) << 3;
    const u16* Ard = &As[(wm + lr) * LDAp + kq];
    const u16* Brd = &Bs[(wn + lr) * LDAp + kq];

    f32x4 acc[4][4];
#pragma unroll
    for (int i = 0; i < 4; ++i)
#pragma unroll
        for (int j = 0; j < 4; ++j) acc[i][j] = (f32x4){0.f, 0.f, 0.f, 0.f};

    for (int k0 = 0; k0 < K; k0 += 32) {
        uint4 a0 = *(const uint4*)(Ag + k0);
        uint4 a1 = *(const uint4*)(Ag + (size_t)64 * K + k0);
        uint4 b0 = *(const uint4*)(Wg + k0);
        uint4 b1 = *(const uint4*)(Wg + (size_t)64 * K + k0);
        __syncthreads();
        *(uint4*)AsW = a0;
        *(uint4*)(AsW + 64 * LDAp) = a1;
        *(uint4*)BsW = b0;
        *(uint4*)(BsW + 64 * LDAp) = b1;
        __syncthreads();
        bf16x8 af[4], bfr[4];
#pragma unroll
        for (int i = 0; i < 4; ++i) {
            af[i] = *(const bf16x8*)(Ard + i * 16 * LDAp);
            bfr[i] = *(const bf16x8*)(Brd + i * 16 * LDAp);
        }
#pragma unroll
        for (int i = 0; i < 4; ++i)
#pragma unroll
            for (int j = 0; j < 4; ++j)
                acc[i][j] = __builtin_amdgcn_mfma_f32_16x16x32_bf16(af[i], bfr[j], acc[i][j], 0, 0, 0);
    }

    int rq = (lane >> 4) << 2;
#pragma unroll
    for (int i = 0; i < 4; ++i) {
#pragma unroll
        for (int j = 0; j < 4; ++j) {
            int n = n0 + wn + j * 16 + lr;
            float bs = bias[n];
            size_t base = (size_t)(m0 + wm + i * 16 + rq) * N + n;
#pragma unroll
            for (int r = 0; r < 4; ++r)
                C[base + (size_t)r * N] = acc[i][j][r] + bs;
        }
    }
}

// ---------------- encoder step (fallback path, fp32) ----------------
__global__ __launch_bounds__(256) void k_enc_step(
    const float* __restrict__ gxf, const float* __restrict__ gxb,
    const float* __restrict__ whf, const float* __restrict__ whb,
    const float* __restrict__ hfp, const float* __restrict__ cfp, float* __restrict__ hfn, float* __restrict__ cfn,
    const float* __restrict__ hbp, const float* __restrict__ cbp, float* __restrict__ hbn, float* __restrict__ cbn,
    float* __restrict__ hid, float* __restrict__ cel, int t) {
    int dir = blockIdx.z;
    const float* gx = dir ? gxb : gxf;
    const float* wh = dir ? whb : whf;
    const float* hp = dir ? hbp : hfp;
    const float* cp = dir ? cbp : cfp;
    float* hn = dir ? hbn : hfn;
    float* cn = dir ? cbn : cfn;
    int hoff = dir ? HHc : 0;
    int b = blockIdx.y;
    int chunk = blockIdx.x;
    int tid = threadIdx.x;
    __shared__ float hs[HHc];
    __shared__ float gv[4][64];
    hs[tid] = hp[b * HHc + tid];
    __syncthreads();
    int gate = tid >> 6;
    int jj = (chunk << 6) + (tid & 63);
    int n = gate * HHc + jj;
    const float* w = wh + (size_t)n * HHc;
    float s = gx[(size_t)(b * Tc + t) * (4 * HHc) + n];
#pragma unroll 8
    for (int k = 0; k < HHc; k += 4) {
        float4 wv = *(const float4*)(w + k);
        s += wv.x * hs[k] + wv.y * hs[k + 1] + wv.z * hs[k + 2] + wv.w * hs[k + 3];
    }
    gv[gate][tid & 63] = s;
    __syncthreads();
    if (tid < 64) {
        int j = (chunk << 6) + tid;
        float c = sigm(gv[1][tid]) * cp[b * HHc + j] + sigm(gv[0][tid]) * tanhf(gv[2][tid]);
        float h = sigm(gv[3][tid]) * tanhf(c);
        hn[b * HHc + j] = h;
        cn[b * HHc + j] = c;
        size_t o = (size_t)(b * Tc + t) * Hc + hoff + j;
        hid[o] = h;
        cel[o] = c;
    }
}

// ---------------- persistent encoder: W_hh bf16 in VGPRs, per-(dir,b) 4-block group sync ----------------
// grid dim3(4, Bc, 2) = 256 blocks x 256 threads. h exchanged via LLC-coherent agent atomics.
__global__ __launch_bounds__(256, 1) void k_enc_all2(
    const float* __restrict__ gxf, const float* __restrict__ gxb,
    const u16* __restrict__ whfb, const u16* __restrict__ whbb,
    float* __restrict__ hx,   // [2][2*Bc][HHc] ping-pong
    int* __restrict__ cnt,    // [2*Bc][Tc]
    float* __restrict__ hid, float* __restrict__ cel) {
    int slice = blockIdx.x, b = blockIdx.y, dir = blockIdx.z, tid = threadIdx.x;
    const float* gx = dir ? gxb : gxf;
    const u16* wb = dir ? whbb : whfb;
    int g = tid >> 6, jj = tid & 63;
    int j0 = slice << 6;
    int n = g * HHc + j0 + jj;
    int grp = dir * Bc + b;
    // register-resident W row: 256 bf16 packed in 128 u32
    u32 w[128];
    {
        const uint4* wr = (const uint4*)(wb + (size_t)n * HHc);
#pragma unroll
        for (int i = 0; i < 32; ++i) {
            uint4 v = wr[i];
            w[4 * i + 0] = v.x; w[4 * i + 1] = v.y; w[4 * i + 2] = v.z; w[4 * i + 3] = v.w;
        }
    }
    __shared__ float hs[HHc];
    __shared__ float gv[4][64];
    float cpriv = 0.0f;
    int* mycnt = cnt + grp * Tc;
    for (int t = 0; t < Tc; ++t) {
        if (t == 0) {
            hs[tid] = 0.0f;
        } else {
            const float* src = hx + ((size_t)(((t - 1) & 1) * 2 * Bc) + grp) * HHc;
            hs[tid] = __hip_atomic_load(&src[tid], __ATOMIC_RELAXED, __HIP_MEMORY_SCOPE_AGENT);
        }
        __syncthreads();
        float s = gx[(size_t)(b * Tc + t) * (4 * HHc) + n];
#pragma unroll
        for (int k2 = 0; k2 < 128; ++k2) {
            u32 pk = w[k2];
            float lo = __uint_as_float(pk << 16);
            float hi = __uint_as_float(pk & 0xFFFF0000u);
            float2 hv = *(const float2*)&hs[2 * k2];
            s += lo * hv.x + hi * hv.y;
        }
        gv[g][jj] = s;
        __syncthreads();
        if (tid < 64) {
            int j = j0 + tid;
            float c = sigm(gv[1][tid]) * cpriv + sigm(gv[0][tid]) * tanhf(gv[2][tid]);
            float h = sigm(gv[3][tid]) * tanhf(c);
            cpriv = c;
            size_t o = (size_t)(b * Tc + t) * Hc + dir * HHc + j;
            hid[o] = h;
            cel[o] = c;
            if (t < Tc - 1) {
                float* dst = hx + ((size_t)((t & 1) * 2 * Bc) + grp) * HHc;
                __hip_atomic_store(&dst[j], h, __ATOMIC_RELAXED, __HIP_MEMORY_SCOPE_AGENT);
            }
        }
        if (t < Tc - 1) {
            __syncthreads();  // drains vmcnt: h stores at LLC
            if (tid == 0) {
                __hip_atomic_fetch_add(&mycnt[t], 1, __ATOMIC_RELEASE, __HIP_MEMORY_SCOPE_AGENT);
                long it = 0;
                while (__hip_atomic_load(&mycnt[t], __ATOMIC_RELAXED, __HIP_MEMORY_SCOPE_AGENT) < 4) {
                    __builtin_amdgcn_s_sleep(2);
                    if (++it > 50000000L) break;
                }
                (void)__hip_atomic_load(&mycnt[t], __ATOMIC_ACQUIRE, __HIP_MEMORY_SCOPE_AGENT);
            }
            __syncthreads();
        }
    }
}

// ---------------- mean over T ----------------
__global__ void k_mean(const float* __restrict__ hid, const float* __restrict__ cel,
                       float* __restrict__ dh, float* __restrict__ dc) {
    int b = blockIdx.x, tid = threadIdx.x;  // 256
    for (int j = tid; j < Hc; j += 256) {
        float sh = 0.f, sc_ = 0.f;
        for (int t = 0; t < Tc; ++t) {
            size_t o = (size_t)(b * Tc + t) * Hc + j;
            sh += hid[o];
            sc_ += cel[o];
        }
        dh[b * Hc + j] = sh * (1.0f / Tc);
        dc[b * Hc + j] = sc_ * (1.0f / Tc);
    }
}

// ---------------- decoder LSTM step (fallback path, fp32) ----------------
__global__ __launch_bounds__(256) void k_dec_step(const float* __restrict__ gy, const float* __restrict__ whd,
                                                  const float* __restrict__ hprev, int hstride,
                                                  const float* __restrict__ cp, float* __restrict__ cn,
                                                  float* __restrict__ outH, int t) {
    int b = blockIdx.y;
    int chunk = blockIdx.x;
    int tid = threadIdx.x;
    __shared__ float hs[Hc];
    __shared__ float gv[4][64];
    hs[tid] = hprev[(size_t)b * hstride + tid];
    hs[tid + 256] = hprev[(size_t)b * hstride + tid + 256];
    __syncthreads();
    int gate = tid >> 6;
    int jj = (chunk << 6) + (tid & 63);
    int n = gate * Hc + jj;
    const float* w = whd + (size_t)n * Hc;
    float s = gy[(size_t)(b * TYc + t) * (4 * Hc) + n];
#pragma unroll 8
    for (int k = 0; k < Hc; k += 4) {
        float4 wv = *(const float4*)(w + k);
        s += wv.x * hs[k] + wv.y * hs[k + 1] + wv.z * hs[k + 2] + wv.w * hs[k + 3];
    }
    gv[gate][tid & 63] = s;
    __syncthreads();
    if (tid < 64) {
        int j = (chunk << 6) + tid;
        float c = sigm(gv[1][tid]) * cp[b * Hc + j] + sigm(gv[0][tid]) * tanhf(gv[2][tid]);
        float h = sigm(gv[3][tid]) * tanhf(c);
        cn[b * Hc + j] = c;
        outH[(size_t)(b * TYc + t) * (2 * Hc) + j] = h;
    }
}

// ---------------- persistent decoder: W_hh bf16 in VGPRs, per-b 8-block group sync ----------------
// grid dim3(8, Bc) = 256 blocks x 256 threads.
__global__ __launch_bounds__(256, 1) void k_dec_all2(
    const float* __restrict__ gy, const u16* __restrict__ whdb,
    const float* __restrict__ dh0, const float* __restrict__ dc0,
    float* __restrict__ hx,   // [2][Bc][Hc]
    int* __restrict__ cnt,    // [Bc][TYc]
    float* __restrict__ outH) {
    int slice = blockIdx.x, b = blockIdx.y, tid = threadIdx.x;
    int g = tid >> 6, jj = tid & 63;
    int j0 = slice << 6;
    int n = g * Hc + j0 + jj;
    // register-resident W row: 512 bf16 packed in 256 u32
    u32 w[256];
    {
        const uint4* wr = (const uint4*)(whdb + (size_t)n * Hc);
#pragma unroll
        for (int i = 0; i < 64; ++i) {
            uint4 v = wr[i];
            w[4 * i + 0] = v.x; w[4 * i + 1] = v.y; w[4 * i + 2] = v.z; w[4 * i + 3] = v.w;
        }
    }
    __shared__ float hs[Hc];
    __shared__ float gv[4][64];
    float cpriv = (tid < 64) ? dc0[b * Hc + j0 + tid] : 0.0f;
    int* mycnt = cnt + b * TYc;
    for (int t = 0; t < TYc; ++t) {
        if (t == 0) {
            hs[tid] = dh0[b * Hc + tid];
            hs[tid + 256] = dh0[b * Hc + tid + 256];
        } else {
            const float* src = hx + ((size_t)(((t - 1) & 1) * Bc) + b) * Hc;
            hs[tid] = __hip_atomic_load(&src[tid], __ATOMIC_RELAXED, __HIP_MEMORY_SCOPE_AGENT);
            hs[tid + 256] = __hip_atomic_load(&src[tid + 256], __ATOMIC_RELAXED, __HIP_MEMORY_SCOPE_AGENT);
        }
        __syncthreads();
        float s = gy[(size_t)(b * TYc + t) * (4 * Hc) + n];
#pragma unroll
        for (int k2 = 0; k2 < 256; ++k2) {
            u32 pk = w[k2];
            float lo = __uint_as_float(pk << 16);
            float hi = __uint_as_float(pk & 0xFFFF0000u);
            float2 hv = *(const float2*)&hs[2 * k2];
            s += lo * hv.x + hi * hv.y;
        }
        gv[g][jj] = s;
        __syncthreads();
        if (tid < 64) {
            int j = j0 + tid;
            float c = sigm(gv[1][tid]) * cpriv + sigm(gv[0][tid]) * tanhf(gv[2][tid]);
            float h = sigm(gv[3][tid]) * tanhf(c);
            cpriv = c;
            outH[(size_t)(b * TYc + t) * (2 * Hc) + j] = h;
            if (t < TYc - 1) {
                float* dst = hx + ((size_t)((t & 1) * Bc) + b) * Hc;
                __hip_atomic_store(&dst[j], h, __ATOMIC_RELAXED, __HIP_MEMORY_SCOPE_AGENT);
            }
        }
        if (t < TYc - 1) {
            __syncthreads();
            if (tid == 0) {
                __hip_atomic_fetch_add(&mycnt[t], 1, __ATOMIC_RELEASE, __HIP_MEMORY_SCOPE_AGENT);
                long it = 0;
                while (__hip_atomic_load(&mycnt[t], __ATOMIC_RELAXED, __HIP_MEMORY_SCOPE_AGENT) < 8) {
                    __builtin_amdgcn_s_sleep(2);
                    if (++it > 50000000L) break;
                }
                (void)__hip_atomic_load(&mycnt[t], __ATOMIC_ACQUIRE, __HIP_MEMORY_SCOPE_AGENT);
            }
            __syncthreads();
        }
    }
}

// ---------------- batched attention (all (b,t) at once) ----------------
__global__ __launch_bounds__(128) void k_attn_all(const float* __restrict__ hid, float* __restrict__ outH, int t0) {
    int b = blockIdx.x, t = t0 + blockIdx.y, tid = threadIdx.x;  // 128
    __shared__ float hq[Hc];
    __shared__ float sc[Tc];
    __shared__ float red[128];
    const float* hrow = outH + (size_t)(b * TYc + t) * (2 * Hc);
    for (int k = tid; k < Hc; k += 128) hq[k] = hrow[k];
    __syncthreads();
    const float* hr = hid + (size_t)(b * Tc + tid) * Hc;
    float s = 0.f;
#pragma unroll 8
    for (int k = 0; k < Hc; k += 4) {
        float4 hv = *(const float4*)(hr + k);
        s += hv.x * hq[k] + hv.y * hq[k + 1] + hv.z * hq[k + 2] + hv.w * hq[k + 3];
    }
    red[tid] = s;
    __syncthreads();
    for (int o = 64; o > 0; o >>= 1) { if (tid < o) red[tid] = fmaxf(red[tid], red[tid + o]); __syncthreads(); }
    float mx = red[0];
    __syncthreads();
    float e = expf(s - mx);
    sc[tid] = e;
    red[tid] = e;
    __syncthreads();
    for (int o = 64; o > 0; o >>= 1) { if (tid < o) red[tid] += red[tid + o]; __syncthreads(); }
    float inv = 1.0f / red[0];
    for (int j = tid; j < Hc; j += 128) {
        float acc = 0.f;
        for (int tt = 0; tt < Tc; ++tt) acc += sc[tt] * hid[(size_t)(b * Tc + tt) * Hc + j];
        outH[(size_t)(b * TYc + t) * (2 * Hc) + Hc + j] = acc * inv;
    }
}

// ---------------- in-place log-softmax over V ----------------
__global__ __launch_bounds__(256) void k_logsm(float* __restrict__ P) {
    int row = blockIdx.x, tid = threadIdx.x;
    float* p = P + (size_t)row * Vc;
    float m = -1e30f, s = 0.f;
    for (int i = tid; i < Vc; i += 256) {
        float v = p[i];
        float nm = fmaxf(m, v);
        s = s * expf(m - nm) + expf(v - nm);
        m = nm;
    }
    __shared__ float ms[256], ss[256];
    ms[tid] = m; ss[tid] = s;
    __syncthreads();
    for (int o = 128; o > 0; o >>= 1) {
        if (tid < o) {
            float m2 = ms[tid + o], s2 = ss[tid + o];
            float nm = fmaxf(ms[tid], m2);
            ss[tid] = ss[tid] * expf(ms[tid] - nm) + s2 * expf(m2 - nm);
            ms[tid] = nm;
        }
        __syncthreads();
    }
    float lse = ms[0] + logf(ss[0]);
    for (int i = tid; i < Vc; i += 256) p[i] -= lse;
}

extern "C" void kernel_launch(void* const* d_in, const int* in_sizes, int n_in,
                              void* d_out, int out_size, void* d_ws, size_t ws_size,
                              hipStream_t stream) {
    const int* x = (const int*)d_in[0];
    const float* xm = (const float*)d_in[1];
    const int* y = (const int*)d_in[2];
    const float* emb = (const float*)d_in[3];
    const float* w_ih_f = (const float*)d_in[4];
    const float* w_hh_f = (const float*)d_in[5];
    const float* b_ih_f = (const float*)d_in[6];
    const float* b_hh_f = (const float*)d_in[7];
    const float* w_ih_b = (const float*)d_in[8];
    const float* w_hh_b = (const float*)d_in[9];
    const float* b_ih_b = (const float*)d_in[10];
    const float* b_hh_b = (const float*)d_in[11];
    const float* w_ih_d = (const float*)d_in[12];
    const float* w_hh_d = (const float*)d_in[13];
    const float* b_ih_d = (const float*)d_in[14];
    const float* b_hh_d = (const float*)d_in[15];
    const float* W_out = (const float*)d_in[16];
    const float* b_out = (const float*)d_in[17];

    float* out = (float*)d_out;
    float* logp = out;                           // (B*TY, V)
    float* outH = out + (size_t)Bc * TYc * Vc;   // (B*TY, 2H) — final output region

    // Scratch arena inside logp region (dead before the logits GEMM writes it).
    const size_t BTE = (size_t)Bc * Tc * Ec;     // 2,097,152
    const size_t BTYE = (size_t)Bc * TYc * Ec;   // 1,048,576
    u16* xeb = (u16*)out;
    u16* xbeb = xeb + BTE;
    u16* yeb = xbeb + BTE;
    float* gf = out + (2 * BTE + BTYE) / 2;
    float* gb = gf + (size_t)Bc * Tc * 4 * HHc;
    float* gd = gb + (size_t)Bc * Tc * 4 * HHc;
    float* hid = gd + (size_t)Bc * TYc * 4 * Hc;
    float* cel = hid + (size_t)Bc * Tc * Hc;
    float* hA = cel + (size_t)Bc * Tc * Hc;      // fallback state (8 * Bc*HHc)
    float* cA = hA + Bc * HHc;
    float* hB = cA + Bc * HHc;
    float* cB = hB + Bc * HHc;
    float* hA2 = cB + Bc * HHc;                  // backward-dir fallback state
    float* cA2 = hA2 + Bc * HHc;
    float* hB2 = cA2 + Bc * HHc;
    float* cB2 = hB2 + Bc * HHc;
    float* dh0 = cB2 + Bc * HHc;
    float* dc0 = dh0 + Bc * Hc;
    float* c0 = dc0 + Bc * Hc;
    float* c1 = c0 + Bc * Hc;
    float* hxe = c1 + Bc * Hc;                   // [2][2*Bc][HHc] = 32768
    float* hxd = hxe + (size_t)2 * 2 * Bc * HHc; // [2][Bc][Hc]   = 32768
    int* cnt_e = (int*)(hxd + (size_t)2 * Bc * Hc);  // 2*Bc*Tc = 8192
    int* cnt_d = cnt_e + 2 * Bc * Tc;                // Bc*TYc  = 2048
    float* bsf = (float*)(cnt_d + Bc * TYc);
    float* bsb = bsf + 4 * HHc;
    float* bsd = bsb + 4 * HHc;
    u16* wfb = (u16*)(bsd + 4 * Hc);
    u16* wbb = wfb + (size_t)4 * HHc * Ec;
    u16* wdb = wbb + (size_t)4 * HHc * Ec;
    u16* whfb = wdb + (size_t)4 * Hc * Ec;       // recurrent weights bf16
    u16* whbb = whfb + (size_t)4 * HHc * HHc;
    u16* whdb = whbb + (size_t)4 * HHc * HHc;
    int* xb = (int*)(whdb + (size_t)4 * Hc * Hc);

    (void)in_sizes; (void)n_in; (void)out_size;

    k_rev<<<Bc, 128, 0, stream>>>(x, xm, xb);
    k_zero<<<(8 * Bc * HHc + 255) / 256, 256, 0, stream>>>(hA, 8 * Bc * HHc);
    k_zero<<<(2 * Bc * Tc + Bc * TYc + 255) / 256, 256, 0, stream>>>((float*)cnt_e, 2 * Bc * Tc + Bc * TYc);
    k_embed<<<2 * Bc * Tc + Bc * TYc, 128, 0, stream>>>(x, xb, y, emb, xeb, xbeb, yeb);

    // cast weights to bf16, fold biases
    k_castv<<<(4 * HHc * Ec / 4 + 255) / 256, 256, 0, stream>>>(w_ih_f, wfb, 4 * HHc * Ec);
    k_castv<<<(4 * HHc * Ec / 4 + 255) / 256, 256, 0, stream>>>(w_ih_b, wbb, 4 * HHc * Ec);
    k_castv<<<(4 * Hc * Ec / 4 + 255) / 256, 256, 0, stream>>>(w_ih_d, wdb, 4 * Hc * Ec);
    k_castv<<<(4 * HHc * HHc / 4 + 255) / 256, 256, 0, stream>>>(w_hh_f, whfb, 4 * HHc * HHc);
    k_castv<<<(4 * HHc * HHc / 4 + 255) / 256, 256, 0, stream>>>(w_hh_b, whbb, 4 * HHc * HHc);
    k_castv<<<(4 * Hc * Hc / 4 + 255) / 256, 256, 0, stream>>>(w_hh_d, whdb, 4 * Hc * Hc);
    k_bsum<<<(4 * HHc + 255) / 256, 256, 0, stream>>>(b_ih_f, b_hh_f, bsf, 4 * HHc);
    k_bsum<<<(4 * HHc + 255) / 256, 256, 0, stream>>>(b_ih_b, b_hh_b, bsb, 4 * HHc);
    k_bsum<<<(4 * Hc + 255) / 256, 256, 0, stream>>>(b_ih_d, b_hh_d, bsd, 4 * Hc);

    // input-side gate GEMMs via bf16 MFMA
    k_gemm_bf16<<<dim3(4 * HHc / 128, Bc * Tc / 128), 256, 0, stream>>>(xeb, wfb, bsf, gf, Bc * Tc, 4 * HHc, Ec);
    k_gemm_bf16<<<dim3(4 * HHc / 128, Bc * Tc / 128), 256, 0, stream>>>(xbeb, wbb, bsb, gb, Bc * Tc, 4 * HHc, Ec);
    k_gemm_bf16<<<dim3(4 * Hc / 128, Bc * TYc / 128), 256, 0, stream>>>(yeb, wdb, bsd, gd, Bc * TYc, 4 * Hc, Ec);

    // encoder recurrence: persistent kernel, per-(dir,b) 4-block groups (fallback: per-step launches)
    {
        const float* a_gxf = gf; const float* a_gxb = gb;
        const u16* a_whf = whfb; const u16* a_whb = whbb;
        float* a_hx = hxe; int* a_cnt = cnt_e;
        float* a_hid = hid; float* a_cel = cel;
        void* args[] = {&a_gxf, &a_gxb, &a_whf, &a_whb, &a_hx, &a_cnt, &a_hid, &a_cel};
        hipError_t e = hipLaunchCooperativeKernel(reinterpret_cast<void*>(k_enc_all2),
                                                  dim3(4, Bc, 2), dim3(256), args, 0, stream);
        if (e != hipSuccess) {
            for (int t = 0; t < Tc; ++t) {
                const float* hp = (t & 1) ? hB : hA;
                const float* cp = (t & 1) ? cB : cA;
                float* hn = (t & 1) ? hA : hB;
                float* cn = (t & 1) ? cA : cB;
                const float* hp2 = (t & 1) ? hB2 : hA2;
                const float* cp2 = (t & 1) ? cB2 : cA2;
                float* hn2 = (t & 1) ? hA2 : hB2;
                float* cn2 = (t & 1) ? cA2 : cB2;
                k_enc_step<<<dim3(HHc / 64, Bc, 2), 256, 0, stream>>>(
                    gf, gb, w_hh_f, w_hh_b,
                    hp, cp, hn, cn, hp2, cp2, hn2, cn2, hid, cel, t);
            }
        }
    }

    k_mean<<<Bc, 256, 0, stream>>>(hid, cel, dh0, dc0);

    // decoder recurrence: persistent kernel, per-b 8-block groups (fallback: per-step launches)
    {
        const float* a_gy = gd; const u16* a_whd = whdb;
        const float* a_dh0 = dh0; const float* a_dc0 = dc0;
        float* a_hx = hxd; int* a_cnt = cnt_d; float* a_oH = outH;
        void* args[] = {&a_gy, &a_whd, &a_dh0, &a_dc0, &a_hx, &a_cnt, &a_oH};
        hipError_t e = hipLaunchCooperativeKernel(reinterpret_cast<void*>(k_dec_all2),
                                                  dim3(8, Bc), dim3(256), args, 0, stream);
        if (e != hipSuccess) {
            for (int t = 0; t < TYc; ++t) {
                const float* hprev = (t == 0) ? dh0 : (outH + (size_t)(t - 1) * (2 * Hc));
                int hstride = (t == 0) ? Hc : TYc * 2 * Hc;
                const float* cp = (t == 0) ? dc0 : ((t & 1) ? c1 : c0);
                float* cn = (t & 1) ? c0 : c1;
                k_dec_step<<<dim3(Hc / 64, Bc), 256, 0, stream>>>(gd, w_hh_d, hprev, hstride, cp, cn, outH, t);
            }
        }
    }

    // batched attention over all (b, t) — out of the recurrence critical path
    k_attn_all<<<dim3(Bc, TYc), 128, 0, stream>>>(hid, outH, 0);

    // logits = outH @ W_out^T + b_out
    const int nW = Vc * 2 * Hc;
    const int nA = Bc * TYc * 2 * Hc;
    size_t need = ((size_t)nW + nA) * sizeof(u16);
    if (ws_size >= need) {
        u16* Wb = (u16*)d_ws;
        u16* Ab = Wb + nW;
        k_cast<<<((nW + nA) / 4 + 255) / 256, 256, 0, stream>>>(W_out, outH, Wb, Ab, nW, nA);
        k_gemm_bf16<<<dim3(Vc / 128, Bc * TYc / 128), 256, 0, stream>>>(Ab, Wb, b_out, logp, Bc * TYc, Vc, 2 * Hc);
    } else {
        k_gemm_nt<<<dim3(Vc / 64, Bc * TYc / 64), 256, 0, stream>>>(outH, W_out, b_out, nullptr, logp, Bc * TYc, Vc, 2 * Hc);
    }
    k_logsm<<<Bc * TYc, 256, 0, stream>>>(logp);
}